// Round 12
// baseline (502.987 us; speedup 1.0000x reference)
//
#include <hip/hip_runtime.h>
#include <hip/hip_bf16.h>

// GCN: 3x (GEMM 64x64 -> sym-norm gather via CSR) -> mean-pool -> linear.
// N=100000 nodes, E=1200000 edges, 128 graphs, D=64, classes=10.
// R8: bucketed CSR build + wave-per-node gather (bf16 H'): 362us.
// R9 (streamed LDS scatter) REVERTED: latency-bound, 422us/layer.
// R11: gather+pool fusion REVERTED: 6.4M f32 atomics onto 8192 gsum addrs
//    (~780 serialized RMW/addr) = 112us vs 49+25 split. Kept: bf16
//    activations, packed edge build, cnt fused into count_k.
// R12: gather2_k = 2 edges/wave via uint(2xbf16)/lane + shfl(lane^32) merge
//    (2x edges in flight, half the instructions); gemm k-loop LDS->shfl;
//    run-length pool_k restored (bf16 input).

#define N_NODES 100000
#define N_EDGES 1200000
#define N_GRAPHS 128
#define D 64
#define N_CLASSES 10

#define NB 512          // destination buckets
#define BSZ 196         // nodes per bucket (196*512 = 100352 >= N)
#define PEB 4096        // edges per partition block
#define PEB4 (PEB/4)

typedef unsigned short ushort_t;
typedef unsigned int uint_t;

__device__ __forceinline__ float bf2f(ushort_t u) {
    union { unsigned int i; float f; } v;
    v.i = ((unsigned int)u) << 16;
    return v.f;
}
__device__ __forceinline__ ushort_t f2bf(float f) {
    __hip_bfloat16 hb = __float2bfloat16(f);
    return *(ushort_t*)&hb;
}

// ---- init: zero bucket counts + pool accumulators ----
__global__ void init_k(int* __restrict__ bcount,
                       float* __restrict__ gsum, float* __restrict__ cnt) {
    int i = blockIdx.x * 256 + threadIdx.x;
    if (i < NB) bcount[i] = 0;
    if (i < N_GRAPHS * D) gsum[i] = 0.0f;
    if (i < N_GRAPHS) cnt[i] = 0.0f;
}

// ---- count: LDS histogram of col/BSZ -> bcount; batch histogram -> cnt ----
__global__ void count_k(const int4* __restrict__ col4, int* __restrict__ bcount,
                        const int* __restrict__ batch, float* __restrict__ cnt,
                        int E4, int n) {
    __shared__ int h[NB];
    __shared__ int bh[N_GRAPHS];
    for (int i = threadIdx.x; i < NB; i += 256) h[i] = 0;
    if (threadIdx.x < N_GRAPHS) bh[threadIdx.x] = 0;
    __syncthreads();
    int base = blockIdx.x * PEB4;
#pragma unroll
    for (int k = 0; k < 4; ++k) {
        int idx = base + k * 256 + threadIdx.x;
        if (idx < E4) {
            int4 c = col4[idx];
            atomicAdd(&h[c.x / BSZ], 1);
            atomicAdd(&h[c.y / BSZ], 1);
            atomicAdd(&h[c.z / BSZ], 1);
            atomicAdd(&h[c.w / BSZ], 1);
        }
    }
    for (int i = blockIdx.x * 256 + threadIdx.x; i < n; i += gridDim.x * 256)
        atomicAdd(&bh[batch[i]], 1);
    __syncthreads();
    for (int i = threadIdx.x; i < NB; i += 256)
        if (h[i]) atomicAdd(&bcount[i], h[i]);
    if (threadIdx.x < N_GRAPHS && bh[threadIdx.x])
        atomicAdd(&cnt[threadIdx.x], (float)bh[threadIdx.x]);
}

// ---- exclusive scan of bcount[512] -> bstart, bcursor (one block) ----
__global__ void scan_k(const int* __restrict__ bcount, int* __restrict__ bstart,
                       int* __restrict__ bcursor) {
    __shared__ int s[NB];
    int t = threadIdx.x;
    int v0 = bcount[t];
    s[t] = v0;
    __syncthreads();
    for (int off = 1; off < NB; off <<= 1) {
        int v = (t >= off) ? s[t - off] : 0;
        __syncthreads();
        s[t] += v;
        __syncthreads();
    }
    int ex = s[t] - v0;
    bstart[t] = ex;
    bcursor[t] = ex;
}

// ---- scatter edges into bucket-major packed array (src<<8 | dstLocal) ----
__global__ void scatter_k(const int4* __restrict__ row4, const int4* __restrict__ col4,
                          int* __restrict__ bcursor, int* __restrict__ part, int E4) {
    __shared__ int h[NB], gb[NB], c2[NB];
    for (int i = threadIdx.x; i < NB; i += 256) { h[i] = 0; c2[i] = 0; }
    __syncthreads();
    int base = blockIdx.x * PEB4;
    int4 rr[4], cc[4];
    bool ok[4];
#pragma unroll
    for (int k = 0; k < 4; ++k) {
        int idx = base + k * 256 + threadIdx.x;
        ok[k] = idx < E4;
        if (ok[k]) {
            rr[k] = row4[idx];
            cc[k] = col4[idx];
            atomicAdd(&h[cc[k].x / BSZ], 1);
            atomicAdd(&h[cc[k].y / BSZ], 1);
            atomicAdd(&h[cc[k].z / BSZ], 1);
            atomicAdd(&h[cc[k].w / BSZ], 1);
        }
    }
    __syncthreads();
    for (int i = threadIdx.x; i < NB; i += 256)
        if (h[i]) gb[i] = atomicAdd(&bcursor[i], h[i]);
    __syncthreads();
#pragma unroll
    for (int k = 0; k < 4; ++k) {
        if (ok[k]) {
            int r[4] = { rr[k].x, rr[k].y, rr[k].z, rr[k].w };
            int c[4] = { cc[k].x, cc[k].y, cc[k].z, cc[k].w };
#pragma unroll
            for (int j = 0; j < 4; ++j) {
                int bk = c[j] / BSZ;
                int dl = c[j] - bk * BSZ;
                int rk = atomicAdd(&c2[bk], 1);
                part[gb[bk] + rk] = (r[j] << 8) | dl;
            }
        }
    }
}

// ---- per-bucket counting sort by dstLocal: csr + deg/dinv/cursor ----
__global__ void sortbuild_k(const int* __restrict__ part, const int* __restrict__ bstart,
                            const int* __restrict__ bcount, int* __restrict__ csr,
                            int* __restrict__ deg, int* __restrict__ cursor,
                            float* __restrict__ dinv) {
    __shared__ int h[256], st[256], c2[256];
    int b = blockIdx.x, t = threadIdx.x;
    int ebeg = bstart[b];
    int cntE = bcount[b];
    h[t] = 0; c2[t] = 0;
    __syncthreads();
    for (int e = ebeg + t; e < ebeg + cntE; e += 256)
        atomicAdd(&h[part[e] & 255], 1);
    __syncthreads();
    int hv = h[t];
    for (int off = 1; off < 256; off <<= 1) {
        int v = (t >= off) ? h[t - off] : 0;
        __syncthreads();
        h[t] += v;
        __syncthreads();
    }
    st[t] = h[t] - hv;
    __syncthreads();
    int node = b * BSZ + t;
    if (t < BSZ && node < N_NODES) {
        deg[node] = hv;
        dinv[node] = rsqrtf((float)(hv + 1));
        cursor[node] = ebeg + st[t] + hv;   // global segment END
    }
    for (int e = ebeg + t; e < ebeg + cntE; e += 256) {
        int p = part[e];
        int cl = p & 255;
        int rk = atomicAdd(&c2[cl], 1);
        csr[ebeg + st[cl] + rk] = p >> 8;
    }
}

// ---- layer1 GEMM: H'[r] = (X[r] @ W) * dinv[r], X f32 -> H bf16 (shfl) ----
__global__ __launch_bounds__(256) void gemm_f32_k(
        const float* __restrict__ X, const float* __restrict__ W,
        const float* __restrict__ dinv, ushort_t* __restrict__ H, int n) {
    int tid = threadIdx.x, wave = tid >> 6, lane = tid & 63;
    float wcol[D];
#pragma unroll
    for (int k = 0; k < D; ++k) wcol[k] = W[k * D + lane];
    for (int row0 = blockIdx.x * 4; row0 < n; row0 += gridDim.x * 4) {
        int row = row0 + wave;
        if (row < n) {
            float xv = X[(size_t)row * D + lane];
            float a0 = 0.0f, a1 = 0.0f;
#pragma unroll
            for (int k = 0; k < D; k += 2) {
                a0 += __shfl(xv, k) * wcol[k];
                a1 += __shfl(xv, k + 1) * wcol[k + 1];
            }
            H[(size_t)row * D + lane] = f2bf((a0 + a1) * dinv[row]);
        }
    }
}

// ---- layers2/3 GEMM: H'[r] = (relu(U[r]) @ W) * dinv[r], bf16 -> bf16 ----
__global__ __launch_bounds__(256) void gemm_bf16_k(
        const ushort_t* __restrict__ U, const float* __restrict__ W,
        const float* __restrict__ dinv, ushort_t* __restrict__ H, int n) {
    int tid = threadIdx.x, wave = tid >> 6, lane = tid & 63;
    float wcol[D];
#pragma unroll
    for (int k = 0; k < D; ++k) wcol[k] = W[k * D + lane];
    for (int row0 = blockIdx.x * 4; row0 < n; row0 += gridDim.x * 4) {
        int row = row0 + wave;
        if (row < n) {
            float xv = fmaxf(bf2f(U[(size_t)row * D + lane]), 0.0f);
            float a0 = 0.0f, a1 = 0.0f;
#pragma unroll
            for (int k = 0; k < D; k += 2) {
                a0 += __shfl(xv, k) * wcol[k];
                a1 += __shfl(xv, k + 1) * wcol[k + 1];
            }
            H[(size_t)row * D + lane] = f2bf((a0 + a1) * dinv[row]);
        }
    }
}

// ---- gather2: 2 edges/wave. Hp2/O2 = bf16 rows viewed as uint[32].
//      lanes 0-31 serve edge k (half=0), lanes 32-63 edge k+1; merge via
//      shfl(lane^32). O[c] = bf16( b + dinv[c]*(H'[c] + sum H'[r]) ). ----
__global__ void gather2_k(const uint_t* __restrict__ Hp2, const int* __restrict__ csr,
                          const int* __restrict__ cursor, const int* __restrict__ deg,
                          const float* __restrict__ dinv, const float* __restrict__ b,
                          uint_t* __restrict__ O2, int n) {
    int c = blockIdx.x * 4 + (threadIdx.x >> 6);
    if (c >= n) return;
    int lane = threadIdx.x & 63;
    int half = lane >> 5;
    int col = lane & 31;
    int end = cursor[c];
    int dg = deg[c];
    float ax = 0.0f, ay = 0.0f;
    for (int j = end - dg; j < end; j += 64) {
        int idx = j + lane;
        int s = (idx < end) ? csr[idx] : 0;
        int m = min(64, end - j);
        int k = 0;
        for (; k + 8 <= m; k += 8) {
#pragma unroll
            for (int p = 0; p < 4; ++p) {
                int eA = __shfl(s, k + 2 * p);
                int eB = __shfl(s, k + 2 * p + 1);
                int src = half ? eB : eA;
                uint_t u = Hp2[(size_t)src * 32 + col];
                ax += bf2f((ushort_t)(u & 0xffff));
                ay += bf2f((ushort_t)(u >> 16));
            }
        }
        for (; k + 2 <= m; k += 2) {
            int eA = __shfl(s, k);
            int eB = __shfl(s, k + 1);
            int src = half ? eB : eA;
            uint_t u = Hp2[(size_t)src * 32 + col];
            ax += bf2f((ushort_t)(u & 0xffff));
            ay += bf2f((ushort_t)(u >> 16));
        }
        if (k < m) {                     // odd tail: half 0 only
            int eA = __shfl(s, k);
            if (!half) {
                uint_t u = Hp2[(size_t)eA * 32 + col];
                ax += bf2f((ushort_t)(u & 0xffff));
                ay += bf2f((ushort_t)(u >> 16));
            }
        }
    }
    // merge halves
    float bx = __shfl(ax, lane ^ 32);
    float by = __shfl(ay, lane ^ 32);
    ax += bx; ay += by;
    if (half == 0) {
        uint_t su = Hp2[(size_t)c * 32 + col];
        ax += bf2f((ushort_t)(su & 0xffff));
        ay += bf2f((ushort_t)(su >> 16));
        float2 bb = ((const float2*)b)[col];
        float di = dinv[c];
        uint_t lo = f2bf(bb.x + di * ax);
        uint_t hi = f2bf(bb.y + di * ay);
        O2[(size_t)c * 32 + col] = lo | (hi << 16);
    }
}

// ---- mean-pool: wave per 64-node chunk (sorted batch run-length), bf16 in ----
#define POOL_CHUNK 64
__global__ void pool_k(const ushort_t* __restrict__ H, const int* __restrict__ batch,
                       float* __restrict__ gsum, int n) {
    int wid = blockIdx.x * 4 + (threadIdx.x >> 6);
    int lane = threadIdx.x & 63;
    int start = wid * POOL_CHUNK;
    if (start >= n) return;
    int m = min(POOL_CHUNK, n - start);
    int bv = batch[min(start + lane, n - 1)];
    int cur = __shfl(bv, 0);
    float acc = 0.0f;
    for (int k = 0; k < m; ++k) {
        int bb = __shfl(bv, k);
        if (bb != cur) {
            atomicAdd(&gsum[cur * D + lane], acc);
            cur = bb; acc = 0.0f;
        }
        acc += bf2f(H[(size_t)(start + k) * D + lane]);
    }
    atomicAdd(&gsum[cur * D + lane], acc);
}

// ---- out[b][c] = (gsum[b]/cnt[b]) @ linW + linb ----
__global__ void final_k(const float* __restrict__ gsum, const float* __restrict__ cnt,
                        const float* __restrict__ linW, const float* __restrict__ linb,
                        float* __restrict__ out) {
    int tid = blockIdx.x * 256 + threadIdx.x;
    if (tid >= N_GRAPHS * N_CLASSES) return;
    int b = tid / N_CLASSES, c = tid % N_CLASSES;
    float inv = 1.0f / fmaxf(cnt[b], 1.0f);
    float acc = linb[c];
#pragma unroll
    for (int k = 0; k < D; ++k)
        acc += gsum[b * D + k] * inv * linW[k * N_CLASSES + c];
    out[tid] = acc;
}

extern "C" void kernel_launch(void* const* d_in, const int* in_sizes, int n_in,
                              void* d_out, int out_size, void* d_ws, size_t ws_size,
                              hipStream_t stream) {
    const float* x    = (const float*)d_in[0];
    const int*   ei   = (const int*)  d_in[1];
    const int*   batch= (const int*)  d_in[2];
    const float* W1   = (const float*)d_in[3];
    const float* b1   = (const float*)d_in[4];
    const float* W2   = (const float*)d_in[5];
    const float* b2   = (const float*)d_in[6];
    const float* W3   = (const float*)d_in[7];
    const float* b3   = (const float*)d_in[8];
    const float* linW = (const float*)d_in[9];
    const float* linb = (const float*)d_in[10];
    float* out = (float*)d_out;

    const int N = N_NODES, E = N_EDGES, E4 = N_EDGES / 4;
    const int4* row4 = (const int4*)ei;
    const int4* col4 = (const int4*)(ei + E);

    // workspace layout (4B units), ~36.5MB
    int* wsi = (int*)d_ws;
    float* dinv   = (float*)wsi;                    // 100352
    int*   deg    = wsi + 100352;                   // 100352
    int*   cursor = deg + 100352;                   // 100352
    int*   csr    = cursor + 100352;                // 1200128
    int*   part   = csr + 1200128;                  // 1200128 (packed)
    int*   bcount = part + 1200128;                 // 512
    int*   bstart = bcount + 512;                   // 512
    int*   bcursor= bstart + 512;                   // 512
    ushort_t* bufH = (ushort_t*)(bcursor + 512);    // N*D bf16 (12.8MB)
    ushort_t* bufA = bufH + (size_t)N * D;          // N*D bf16 (12.8MB)
    float* gsum   = (float*)(bufA + (size_t)N * D); // 8192
    float* cnt    = gsum + N_GRAPHS * D;            // 128

    const int nb_part  = (E + PEB - 1) / PEB;       // 293
    const int nb_gather= (N + 3) / 4;               // 25000
    const int nb_gemm  = 2048;
    const int nwaves   = (N + POOL_CHUNK - 1) / POOL_CHUNK;
    const int nb_pool  = (nwaves + 3) / 4;

    // bucketed CSR build
    init_k<<<(N_GRAPHS * D + 255) / 256, 256, 0, stream>>>(bcount, gsum, cnt);
    count_k<<<nb_part, 256, 0, stream>>>(col4, bcount, batch, cnt, E4, N);
    scan_k<<<1, NB, 0, stream>>>(bcount, bstart, bcursor);
    scatter_k<<<nb_part, 256, 0, stream>>>(row4, col4, bcursor, part, E4);
    sortbuild_k<<<NB, 256, 0, stream>>>(part, bstart, bcount, csr, deg, cursor, dinv);

    // layer 1
    gemm_f32_k<<<nb_gemm, 256, 0, stream>>>(x, W1, dinv, bufH, N);
    gather2_k<<<nb_gather, 256, 0, stream>>>((uint_t*)bufH, csr, cursor, deg, dinv, b1,
                                             (uint_t*)bufA, N);
    // layer 2
    gemm_bf16_k<<<nb_gemm, 256, 0, stream>>>(bufA, W2, dinv, bufH, N);
    gather2_k<<<nb_gather, 256, 0, stream>>>((uint_t*)bufH, csr, cursor, deg, dinv, b2,
                                             (uint_t*)bufA, N);
    // layer 3
    gemm_bf16_k<<<nb_gemm, 256, 0, stream>>>(bufA, W3, dinv, bufH, N);
    gather2_k<<<nb_gather, 256, 0, stream>>>((uint_t*)bufH, csr, cursor, deg, dinv, b3,
                                             (uint_t*)bufA, N);

    // pool + classify
    pool_k<<<nb_pool, 256, 0, stream>>>(bufA, batch, gsum, N);
    final_k<<<(N_GRAPHS * N_CLASSES + 255) / 256, 256, 0, stream>>>(gsum, cnt, linW, linb, out);
}

// Round 13
// 364.792 us; speedup vs baseline: 1.3788x; 1.3788x over previous
//
#include <hip/hip_runtime.h>
#include <hip/hip_bf16.h>

// GCN: 3x (GEMM 64x64 -> sym-norm gather via CSR) -> mean-pool -> linear.
// N=100000 nodes, E=1200000 edges, 128 graphs, D=64, classes=10.
// R8: bucketed CSR build + wave-per-node gather (bf16 H'): 362us.
// R9 (streamed LDS scatter) REVERTED: latency-bound.
// R11: gather+pool fusion REVERTED: 780-way gsum atomic contention.
// R12 REVERTED both: shfl k-loop gemm (64 serial ds_bpermute, 78us vs ~28)
//    and 2-edge/wave gather2 (~70us vs 49.7) — LDS broadcast read and
//    64-lane-per-edge loads were already the right idioms.
// R13: best-known composition: R8 skeleton + bf16 activations + packed
//    edge build + cnt fused in count_k + run-length bf16 pool.

#define N_NODES 100000
#define N_EDGES 1200000
#define N_GRAPHS 128
#define D 64
#define N_CLASSES 10

#define NB 512          // destination buckets
#define BSZ 196         // nodes per bucket (196*512 = 100352 >= N)
#define PEB 4096        // edges per partition block
#define PEB4 (PEB/4)

typedef unsigned short ushort_t;

__device__ __forceinline__ float bf2f(ushort_t u) {
    union { unsigned int i; float f; } v;
    v.i = ((unsigned int)u) << 16;
    return v.f;
}
__device__ __forceinline__ ushort_t f2bf(float f) {
    __hip_bfloat16 hb = __float2bfloat16(f);
    return *(ushort_t*)&hb;
}

// ---- init: zero bucket counts + pool accumulators ----
__global__ void init_k(int* __restrict__ bcount,
                       float* __restrict__ gsum, float* __restrict__ cnt) {
    int i = blockIdx.x * 256 + threadIdx.x;
    if (i < NB) bcount[i] = 0;
    if (i < N_GRAPHS * D) gsum[i] = 0.0f;
    if (i < N_GRAPHS) cnt[i] = 0.0f;
}

// ---- count: LDS histogram of col/BSZ -> bcount; batch histogram -> cnt ----
__global__ void count_k(const int4* __restrict__ col4, int* __restrict__ bcount,
                        const int* __restrict__ batch, float* __restrict__ cnt,
                        int E4, int n) {
    __shared__ int h[NB];
    __shared__ int bh[N_GRAPHS];
    for (int i = threadIdx.x; i < NB; i += 256) h[i] = 0;
    if (threadIdx.x < N_GRAPHS) bh[threadIdx.x] = 0;
    __syncthreads();
    int base = blockIdx.x * PEB4;
#pragma unroll
    for (int k = 0; k < 4; ++k) {
        int idx = base + k * 256 + threadIdx.x;
        if (idx < E4) {
            int4 c = col4[idx];
            atomicAdd(&h[c.x / BSZ], 1);
            atomicAdd(&h[c.y / BSZ], 1);
            atomicAdd(&h[c.z / BSZ], 1);
            atomicAdd(&h[c.w / BSZ], 1);
        }
    }
    for (int i = blockIdx.x * 256 + threadIdx.x; i < n; i += gridDim.x * 256)
        atomicAdd(&bh[batch[i]], 1);
    __syncthreads();
    for (int i = threadIdx.x; i < NB; i += 256)
        if (h[i]) atomicAdd(&bcount[i], h[i]);
    if (threadIdx.x < N_GRAPHS && bh[threadIdx.x])
        atomicAdd(&cnt[threadIdx.x], (float)bh[threadIdx.x]);
}

// ---- exclusive scan of bcount[512] -> bstart, bcursor (one block) ----
__global__ void scan_k(const int* __restrict__ bcount, int* __restrict__ bstart,
                       int* __restrict__ bcursor) {
    __shared__ int s[NB];
    int t = threadIdx.x;
    int v0 = bcount[t];
    s[t] = v0;
    __syncthreads();
    for (int off = 1; off < NB; off <<= 1) {
        int v = (t >= off) ? s[t - off] : 0;
        __syncthreads();
        s[t] += v;
        __syncthreads();
    }
    int ex = s[t] - v0;
    bstart[t] = ex;
    bcursor[t] = ex;
}

// ---- scatter edges into bucket-major packed array (src<<8 | dstLocal) ----
__global__ void scatter_k(const int4* __restrict__ row4, const int4* __restrict__ col4,
                          int* __restrict__ bcursor, int* __restrict__ part, int E4) {
    __shared__ int h[NB], gb[NB], c2[NB];
    for (int i = threadIdx.x; i < NB; i += 256) { h[i] = 0; c2[i] = 0; }
    __syncthreads();
    int base = blockIdx.x * PEB4;
    int4 rr[4], cc[4];
    bool ok[4];
#pragma unroll
    for (int k = 0; k < 4; ++k) {
        int idx = base + k * 256 + threadIdx.x;
        ok[k] = idx < E4;
        if (ok[k]) {
            rr[k] = row4[idx];
            cc[k] = col4[idx];
            atomicAdd(&h[cc[k].x / BSZ], 1);
            atomicAdd(&h[cc[k].y / BSZ], 1);
            atomicAdd(&h[cc[k].z / BSZ], 1);
            atomicAdd(&h[cc[k].w / BSZ], 1);
        }
    }
    __syncthreads();
    for (int i = threadIdx.x; i < NB; i += 256)
        if (h[i]) gb[i] = atomicAdd(&bcursor[i], h[i]);
    __syncthreads();
#pragma unroll
    for (int k = 0; k < 4; ++k) {
        if (ok[k]) {
            int r[4] = { rr[k].x, rr[k].y, rr[k].z, rr[k].w };
            int c[4] = { cc[k].x, cc[k].y, cc[k].z, cc[k].w };
#pragma unroll
            for (int j = 0; j < 4; ++j) {
                int bk = c[j] / BSZ;
                int dl = c[j] - bk * BSZ;
                int rk = atomicAdd(&c2[bk], 1);
                part[gb[bk] + rk] = (r[j] << 8) | dl;
            }
        }
    }
}

// ---- per-bucket counting sort by dstLocal: csr + deg/dinv/cursor ----
__global__ void sortbuild_k(const int* __restrict__ part, const int* __restrict__ bstart,
                            const int* __restrict__ bcount, int* __restrict__ csr,
                            int* __restrict__ deg, int* __restrict__ cursor,
                            float* __restrict__ dinv) {
    __shared__ int h[256], st[256], c2[256];
    int b = blockIdx.x, t = threadIdx.x;
    int ebeg = bstart[b];
    int cntE = bcount[b];
    h[t] = 0; c2[t] = 0;
    __syncthreads();
    for (int e = ebeg + t; e < ebeg + cntE; e += 256)
        atomicAdd(&h[part[e] & 255], 1);
    __syncthreads();
    int hv = h[t];
    for (int off = 1; off < 256; off <<= 1) {
        int v = (t >= off) ? h[t - off] : 0;
        __syncthreads();
        h[t] += v;
        __syncthreads();
    }
    st[t] = h[t] - hv;
    __syncthreads();
    int node = b * BSZ + t;
    if (t < BSZ && node < N_NODES) {
        deg[node] = hv;
        dinv[node] = rsqrtf((float)(hv + 1));
        cursor[node] = ebeg + st[t] + hv;   // global segment END
    }
    for (int e = ebeg + t; e < ebeg + cntE; e += 256) {
        int p = part[e];
        int cl = p & 255;
        int rk = atomicAdd(&c2[cl], 1);
        csr[ebeg + st[cl] + rk] = p >> 8;
    }
}

// ---- layer1 GEMM: H'[r] = (X[r] @ W) * dinv[r], X f32 -> H bf16 ----
// W[:,lane] in 64 VGPRs; X row broadcast via LDS same-address read.
__global__ __launch_bounds__(256) void gemm_f32_k(
        const float* __restrict__ X, const float* __restrict__ W,
        const float* __restrict__ dinv, ushort_t* __restrict__ H, int n) {
    __shared__ float Xs[4][D];
    int tid = threadIdx.x, wave = tid >> 6, lane = tid & 63;
    float wcol[D];
#pragma unroll
    for (int k = 0; k < D; ++k) wcol[k] = W[k * D + lane];
    for (int row0 = blockIdx.x * 4; row0 < n; row0 += gridDim.x * 4) {
        int row = row0 + wave;
        if (row < n) {
            Xs[wave][lane] = X[(size_t)row * D + lane];
            float acc = 0.0f;
#pragma unroll
            for (int k = 0; k < D; ++k) acc += Xs[wave][k] * wcol[k];
            H[(size_t)row * D + lane] = f2bf(acc * dinv[row]);
        }
    }
}

// ---- layers2/3 GEMM: H'[r] = (relu(U[r]) @ W) * dinv[r], bf16 -> bf16 ----
__global__ __launch_bounds__(256) void gemm_bf16_k(
        const ushort_t* __restrict__ U, const float* __restrict__ W,
        const float* __restrict__ dinv, ushort_t* __restrict__ H, int n) {
    __shared__ float Xs[4][D];
    int tid = threadIdx.x, wave = tid >> 6, lane = tid & 63;
    float wcol[D];
#pragma unroll
    for (int k = 0; k < D; ++k) wcol[k] = W[k * D + lane];
    for (int row0 = blockIdx.x * 4; row0 < n; row0 += gridDim.x * 4) {
        int row = row0 + wave;
        if (row < n) {
            Xs[wave][lane] = fmaxf(bf2f(U[(size_t)row * D + lane]), 0.0f);
            float acc = 0.0f;
#pragma unroll
            for (int k = 0; k < D; ++k) acc += Xs[wave][k] * wcol[k];
            H[(size_t)row * D + lane] = f2bf(acc * dinv[row]);
        }
    }
}

// ---- gather: O[c] = bf16( b + dinv[c] * (H'[c] + sum_{r in N(c)} H'[r]) ) ----
__global__ void gather_k(const ushort_t* __restrict__ Hp, const int* __restrict__ csr,
                         const int* __restrict__ cursor, const int* __restrict__ deg,
                         const float* __restrict__ dinv, const float* __restrict__ b,
                         ushort_t* __restrict__ O, int n) {
    int c = blockIdx.x * 4 + (threadIdx.x >> 6);
    if (c >= n) return;
    int lane = threadIdx.x & 63;
    int end = cursor[c];
    int dg = deg[c];
    float acc = bf2f(Hp[(size_t)c * D + lane]);
    for (int j = end - dg; j < end; j += 64) {
        int idx = j + lane;
        int s = (idx < end) ? csr[idx] : 0;
        int cnt = min(64, end - j);
        int k = 0;
        for (; k + 4 <= cnt; k += 4) {
            int r0 = __shfl(s, k);
            int r1 = __shfl(s, k + 1);
            int r2 = __shfl(s, k + 2);
            int r3 = __shfl(s, k + 3);
            float v0 = bf2f(Hp[(size_t)r0 * D + lane]);
            float v1 = bf2f(Hp[(size_t)r1 * D + lane]);
            float v2 = bf2f(Hp[(size_t)r2 * D + lane]);
            float v3 = bf2f(Hp[(size_t)r3 * D + lane]);
            acc += v0 + v1 + v2 + v3;
        }
        for (; k < cnt; ++k) {
            int r0 = __shfl(s, k);
            acc += bf2f(Hp[(size_t)r0 * D + lane]);
        }
    }
    O[(size_t)c * D + lane] = f2bf(b[lane] + dinv[c] * acc);
}

// ---- mean-pool: wave per 64-node chunk (sorted batch run-length), bf16 in ----
#define POOL_CHUNK 64
__global__ void pool_k(const ushort_t* __restrict__ H, const int* __restrict__ batch,
                       float* __restrict__ gsum, int n) {
    int wid = blockIdx.x * 4 + (threadIdx.x >> 6);
    int lane = threadIdx.x & 63;
    int start = wid * POOL_CHUNK;
    if (start >= n) return;
    int m = min(POOL_CHUNK, n - start);
    int bv = batch[min(start + lane, n - 1)];
    int cur = __shfl(bv, 0);
    float acc = 0.0f;
    for (int k = 0; k < m; ++k) {
        int bb = __shfl(bv, k);
        if (bb != cur) {
            atomicAdd(&gsum[cur * D + lane], acc);
            cur = bb; acc = 0.0f;
        }
        acc += bf2f(H[(size_t)(start + k) * D + lane]);
    }
    atomicAdd(&gsum[cur * D + lane], acc);
}

// ---- out[b][c] = (gsum[b]/cnt[b]) @ linW + linb ----
__global__ void final_k(const float* __restrict__ gsum, const float* __restrict__ cnt,
                        const float* __restrict__ linW, const float* __restrict__ linb,
                        float* __restrict__ out) {
    int tid = blockIdx.x * 256 + threadIdx.x;
    if (tid >= N_GRAPHS * N_CLASSES) return;
    int b = tid / N_CLASSES, c = tid % N_CLASSES;
    float inv = 1.0f / fmaxf(cnt[b], 1.0f);
    float acc = linb[c];
#pragma unroll
    for (int k = 0; k < D; ++k)
        acc += gsum[b * D + k] * inv * linW[k * N_CLASSES + c];
    out[tid] = acc;
}

extern "C" void kernel_launch(void* const* d_in, const int* in_sizes, int n_in,
                              void* d_out, int out_size, void* d_ws, size_t ws_size,
                              hipStream_t stream) {
    const float* x    = (const float*)d_in[0];
    const int*   ei   = (const int*)  d_in[1];
    const int*   batch= (const int*)  d_in[2];
    const float* W1   = (const float*)d_in[3];
    const float* b1   = (const float*)d_in[4];
    const float* W2   = (const float*)d_in[5];
    const float* b2   = (const float*)d_in[6];
    const float* W3   = (const float*)d_in[7];
    const float* b3   = (const float*)d_in[8];
    const float* linW = (const float*)d_in[9];
    const float* linb = (const float*)d_in[10];
    float* out = (float*)d_out;

    const int N = N_NODES, E = N_EDGES, E4 = N_EDGES / 4;
    const int4* row4 = (const int4*)ei;
    const int4* col4 = (const int4*)(ei + E);

    // workspace layout (4B units), ~36.5MB
    int* wsi = (int*)d_ws;
    float* dinv   = (float*)wsi;                    // 100352
    int*   deg    = wsi + 100352;                   // 100352
    int*   cursor = deg + 100352;                   // 100352
    int*   csr    = cursor + 100352;                // 1200128
    int*   part   = csr + 1200128;                  // 1200128 (packed)
    int*   bcount = part + 1200128;                 // 512
    int*   bstart = bcount + 512;                   // 512
    int*   bcursor= bstart + 512;                   // 512
    ushort_t* bufH = (ushort_t*)(bcursor + 512);    // N*D bf16 (12.8MB)
    ushort_t* bufA = bufH + (size_t)N * D;          // N*D bf16 (12.8MB)
    float* gsum   = (float*)(bufA + (size_t)N * D); // 8192
    float* cnt    = gsum + N_GRAPHS * D;            // 128

    const int nb_part  = (E + PEB - 1) / PEB;       // 293
    const int nb_gather= (N + 3) / 4;               // 25000
    const int nb_gemm  = 2048;
    const int nwaves   = (N + POOL_CHUNK - 1) / POOL_CHUNK;
    const int nb_pool  = (nwaves + 3) / 4;

    // bucketed CSR build
    init_k<<<(N_GRAPHS * D + 255) / 256, 256, 0, stream>>>(bcount, gsum, cnt);
    count_k<<<nb_part, 256, 0, stream>>>(col4, bcount, batch, cnt, E4, N);
    scan_k<<<1, NB, 0, stream>>>(bcount, bstart, bcursor);
    scatter_k<<<nb_part, 256, 0, stream>>>(row4, col4, bcursor, part, E4);
    sortbuild_k<<<NB, 256, 0, stream>>>(part, bstart, bcount, csr, deg, cursor, dinv);

    // layer 1
    gemm_f32_k<<<nb_gemm, 256, 0, stream>>>(x, W1, dinv, bufH, N);
    gather_k<<<nb_gather, 256, 0, stream>>>(bufH, csr, cursor, deg, dinv, b1, bufA, N);
    // layer 2
    gemm_bf16_k<<<nb_gemm, 256, 0, stream>>>(bufA, W2, dinv, bufH, N);
    gather_k<<<nb_gather, 256, 0, stream>>>(bufH, csr, cursor, deg, dinv, b2, bufA, N);
    // layer 3
    gemm_bf16_k<<<nb_gemm, 256, 0, stream>>>(bufA, W3, dinv, bufH, N);
    gather_k<<<nb_gather, 256, 0, stream>>>(bufH, csr, cursor, deg, dinv, b3, bufA, N);

    // pool + classify
    pool_k<<<nb_pool, 256, 0, stream>>>(bufA, batch, gsum, N);
    final_k<<<(N_GRAPHS * N_CLASSES + 255) / 256, 256, 0, stream>>>(gsum, cnt, linW, linb, out);
}